// Round 4
// baseline (2616.985 us; speedup 1.0000x reference)
//
#include <hip/hip_runtime.h>
#include <hip/hip_bf16.h>
#include <math.h>

// B=32, T=128, D_IN=32, H1=1024, H=2048, PEN=1024, C=64, P=4
// Inputs/outputs are FLOAT32 (per the reference dtypes; labels int32).
// Internally: f32 -> bf16 conversion at GEMM staging, bf16 MFMA compute,
// bf16 activations, f32 final outputs. Loose threshold (1.02e-2) admits bf16.

typedef __bf16 bf16_t;
typedef __bf16 bf16x8 __attribute__((ext_vector_type(8)));
typedef float  f32x4  __attribute__((ext_vector_type(4)));

static __device__ __forceinline__ void zero4(f32x4& v) {
  v[0] = 0.0f; v[1] = 0.0f; v[2] = 0.0f; v[3] = 0.0f;
}

template <typename T>
static __device__ __forceinline__ bf16x8 load8_as_bf16(const T* p);
template <>
__device__ __forceinline__ bf16x8 load8_as_bf16<bf16_t>(const bf16_t* p) {
  return *(const bf16x8*)p;
}
template <>
__device__ __forceinline__ bf16x8 load8_as_bf16<float>(const float* p) {
  bf16x8 v;
#pragma unroll
  for (int u = 0; u < 8; ++u) v[u] = (bf16_t)p[u];
  return v;
}

// ---------------------------------------------------------------------------
// GEMM: C[M,N] = act(A[M,K] * Bm[N,K]^T + bias[N]), row-major, bf16 C.
// A/B dtype templated (float inputs converted to bf16 at staging).
// 128x128 tile, BK=32, 256 threads = 4 waves 2x2, wave 64x64 via 4x4
// mfma_f32_16x16x32_bf16. Requires M%128==0, N%128==0, K%32==0.
// ---------------------------------------------------------------------------
template <typename TA, typename TB>
__global__ __launch_bounds__(256) void gemm_bt(
    const TA* __restrict__ A, const TB* __restrict__ Bm,
    const float* __restrict__ bias, bf16_t* __restrict__ C,
    int M, int N, int K, int relu)
{
  __shared__ __align__(16) bf16_t As[128 * 32];
  __shared__ __align__(16) bf16_t Bs[128 * 32];

  const int tid  = threadIdx.x;
  const int lane = tid & 63;
  const int wave = tid >> 6;
  const int q    = lane >> 4;     // quad 0..3
  const int l15  = lane & 15;
  const int wr   = wave >> 1;     // wave m-half
  const int wc   = wave & 1;      // wave n-half
  const int m0   = blockIdx.y * 128;
  const int n0   = blockIdx.x * 128;

  f32x4 acc[4][4];
#pragma unroll
  for (int i = 0; i < 4; ++i)
#pragma unroll
    for (int j = 0; j < 4; ++j) zero4(acc[i][j]);

  const int se = wave * 512 + lane * 8;  // element in a 2048-elem chunk

  const int kt_count = K >> 5;
  for (int kt = 0; kt < kt_count; ++kt) {
    const int k0 = kt << 5;

    bf16x8 av[2], bv[2];
#pragma unroll
    for (int c = 0; c < 2; ++c) {
      const int e   = c * 2048 + se;
      const int row = e >> 5;      // 0..127
      const int col = e & 31;      // 0,8,16,24
      av[c] = load8_as_bf16<TA>(&A [(size_t)(m0 + row) * K + k0 + col]);
      bv[c] = load8_as_bf16<TB>(&Bm[(size_t)(n0 + row) * K + k0 + col]);
    }

    __syncthreads();   // previous iteration's LDS reads complete
#pragma unroll
    for (int c = 0; c < 2; ++c) {
      *(bf16x8*)&As[c * 2048 + se] = av[c];
      *(bf16x8*)&Bs[c * 2048 + se] = bv[c];
    }
    __syncthreads();   // staging visible to all waves

    bf16x8 af[4], bfv[4];
#pragma unroll
    for (int i = 0; i < 4; ++i)
      af[i] = *(const bf16x8*)&As[(wr * 64 + i * 16 + l15) * 32 + q * 8];
#pragma unroll
    for (int j = 0; j < 4; ++j)
      bfv[j] = *(const bf16x8*)&Bs[(wc * 64 + j * 16 + l15) * 32 + q * 8];

#pragma unroll
    for (int i = 0; i < 4; ++i)
#pragma unroll
      for (int j = 0; j < 4; ++j)
        acc[i][j] = __builtin_amdgcn_mfma_f32_16x16x32_bf16(af[i], bfv[j], acc[i][j], 0, 0, 0);
  }

  // Epilogue: C/D layout col = lane&15 (n), row = (lane>>4)*4 + reg (m)
#pragma unroll
  for (int j = 0; j < 4; ++j) {
    const int n = n0 + wc * 64 + j * 16 + l15;
    const float bvl = bias[n];
#pragma unroll
    for (int i = 0; i < 4; ++i) {
      const int mbase = m0 + wr * 64 + i * 16 + q * 4;
#pragma unroll
      for (int r = 0; r < 4; ++r) {
        float v = acc[i][j][r] + bvl;
        if (relu) v = v > 0.0f ? v : 0.0f;
        C[(size_t)(mbase + r) * N + n] = (bf16_t)v;
      }
    }
  }
}

// ---------------------------------------------------------------------------
// f32 -> bf16 bulk convert (8 elems/thread). n8 = n/8.
// ---------------------------------------------------------------------------
__global__ __launch_bounds__(256) void cvt_f32_bf16(
    const float* __restrict__ s, bf16_t* __restrict__ d, int n8)
{
  const int i = blockIdx.x * 256 + threadIdx.x;
  if (i < n8) {
    const float* p = s + (size_t)i * 8;
    bf16x8 v;
#pragma unroll
    for (int u = 0; u < 8; ++u) v[u] = (bf16_t)p[u];
    *(bf16x8*)(d + (size_t)i * 8) = v;
  }
}

// ---------------------------------------------------------------------------
// One GRU time step. Grid = 256 WGs x 256 threads. WG owns 8 h-columns
// j0..j0+7 -> W_hhb rows {j0..}, {2048+j0..}, {4096+j0..} (r,z,n gates).
// MFMA tiles: 2x2 of 16x16 (24 useful gate rows x batch 32), K=2048.
// hprev==nullptr means t==0 (h = 0): skip the matmul.
// W_hhb is the pre-converted bf16 copy; b_hh stays f32.
// ---------------------------------------------------------------------------
__global__ __launch_bounds__(256) void gru_step(
    const bf16_t* __restrict__ W_hhb, const float* __restrict__ b_hh,
    const bf16_t* __restrict__ xp,    bf16_t* __restrict__ hs,
    const bf16_t* __restrict__ hprev, int t)
{
  __shared__ __align__(16) float hp_s[32][33];

  const int tid  = threadIdx.x;
  const int lane = tid & 63;
  const int wave = tid >> 6;
  const int q    = lane >> 4;
  const int l15  = lane & 15;
  const int mt   = wave >> 1;   // m-tile (gate rows)
  const int nt   = wave & 1;    // n-tile (batch)
  const int j0   = blockIdx.x * 8;

  f32x4 acc; zero4(acc);
  if (hprev) {
    const int m_local = mt * 16 + l15;
    int gate = m_local >> 3; if (gate > 2) gate = 2;   // rows 24..31 unused
    const bf16_t* arow = W_hhb + ((size_t)gate * 2048 + j0 + (m_local & 7)) * 2048;
    const int bcol = nt * 16 + l15;
    const bf16_t* brow = hprev + (size_t)bcol * (128 * 2048);

    f32x4 acc0, acc1; zero4(acc0); zero4(acc1);
    for (int k = 0; k < 2048; k += 64) {
      bf16x8 a0 = *(const bf16x8*)&arow[k + q * 8];
      bf16x8 b0 = *(const bf16x8*)&brow[k + q * 8];
      bf16x8 a1 = *(const bf16x8*)&arow[k + 32 + q * 8];
      bf16x8 b1 = *(const bf16x8*)&brow[k + 32 + q * 8];
      acc0 = __builtin_amdgcn_mfma_f32_16x16x32_bf16(a0, b0, acc0, 0, 0, 0);
      acc1 = __builtin_amdgcn_mfma_f32_16x16x32_bf16(a1, b1, acc1, 0, 0, 0);
    }
    acc = acc0 + acc1;
  }

#pragma unroll
  for (int r = 0; r < 4; ++r) {
    const int ml = mt * 16 + q * 4 + r;   // gate-row within 0..31
    if (ml < 24) hp_s[ml][nt * 16 + l15] = acc[r];
  }
  __syncthreads();

  // pointwise: 256 threads -> (b = tid>>3) x (jj = tid&7)
  const int b  = tid >> 3;
  const int jj = tid & 7;
  const int jg = j0 + jj;
  const size_t xrow = (size_t)(b * 128 + t) * 6144;
  const float xr = (float)xp[xrow + jg];
  const float xz = (float)xp[xrow + 2048 + jg];
  const float xn = (float)xp[xrow + 4096 + jg];
  const float hr = hp_s[jj][b]      + b_hh[jg];
  const float hz = hp_s[8 + jj][b]  + b_hh[2048 + jg];
  const float hn = hp_s[16 + jj][b] + b_hh[4096 + jg];
  const float r_ = 1.0f / (1.0f + __expf(-(xr + hr)));
  const float z_ = 1.0f / (1.0f + __expf(-(xz + hz)));
  const float n_ = tanhf(xn + r_ * hn);
  const float hp = hprev ? (float)hprev[(size_t)b * (128 * 2048) + jg] : 0.0f;
  const float hnew = (1.0f - z_) * n_ + z_ * hp;
  hs[((size_t)b * 128 + t) * 2048 + jg] = (bf16_t)hnew;
}

// ---------------------------------------------------------------------------
// Heads: per (b,t): 3 scalar heads + 4 sigmoid heads, 1024-dot each with a
// label-gathered f32 weight row. out_s is bf16, OUTPUT IS FLOAT32.
// ---------------------------------------------------------------------------
__global__ __launch_bounds__(256) void heads_kernel(
    const bf16_t* __restrict__ out_s, const int* __restrict__ labels,
    const float* __restrict__ W4, const float* __restrict__ b4,
    const float* __restrict__ W5, const float* __restrict__ b5,
    const float* __restrict__ W6, const float* __restrict__ b6,
    const float* __restrict__ Wp, const float* __restrict__ bp,
    float* __restrict__ out)
{
  const int bt  = blockIdx.x;
  const int b   = bt >> 7;         // T = 128
  const int lab = labels[b];
  const bf16_t* os  = out_s + (size_t)bt * 1024;
  const float* w4  = W4 + (size_t)lab * 1024;
  const float* w5  = W5 + (size_t)lab * 1024;
  const float* w6  = W6 + (size_t)lab * 1024;
  const float* wp0 = Wp + (size_t)lab * 1024;   // + p*65536 for plane p

  float s[7] = {0, 0, 0, 0, 0, 0, 0};
  for (int d = threadIdx.x; d < 1024; d += 256) {
    const float v = (float)os[d];
    s[0] += v * w4[d];
    s[1] += v * w5[d];
    s[2] += v * w6[d];
    s[3] += v * wp0[d];
    s[4] += v * wp0[65536 + d];
    s[5] += v * wp0[131072 + d];
    s[6] += v * wp0[196608 + d];
  }
#pragma unroll
  for (int i = 0; i < 7; ++i)
    for (int off = 32; off > 0; off >>= 1)
      s[i] += __shfl_down(s[i], off, 64);

  __shared__ float red[4][7];
  const int lane = threadIdx.x & 63, wave = threadIdx.x >> 6;
  if (lane == 0)
    for (int i = 0; i < 7; ++i) red[wave][i] = s[i];
  __syncthreads();
  if (threadIdx.x == 0) {
    float tsum[7];
    for (int i = 0; i < 7; ++i)
      tsum[i] = red[0][i] + red[1][i] + red[2][i] + red[3][i];
    out[bt]        = tsum[0] + b4[lab];
    out[4096 + bt] = tsum[1] + b5[lab];
    out[8192 + bt] = tsum[2] + b6[lab];
#pragma unroll
    for (int p = 0; p < 4; ++p) {
      const float v = tsum[3 + p] + bp[p * 64 + lab];
      out[12288 + p * 4096 + bt] = 1.0f / (1.0f + __expf(-v));
    }
  }
}

// ---------------------------------------------------------------------------
extern "C" void kernel_launch(void* const* d_in, const int* in_sizes, int n_in,
                              void* d_out, int out_size, void* d_ws, size_t ws_size,
                              hipStream_t stream)
{
  const float* x     = (const float*)d_in[0];
  const int*   label = (const int*)d_in[1];
  const float* W1    = (const float*)d_in[2];
  const float* b1    = (const float*)d_in[3];
  const float* W2    = (const float*)d_in[4];
  const float* b2    = (const float*)d_in[5];
  const float* W_ih  = (const float*)d_in[6];
  const float* b_ih  = (const float*)d_in[7];
  const float* W_hh  = (const float*)d_in[8];
  const float* b_hh  = (const float*)d_in[9];
  const float* W3    = (const float*)d_in[10];
  const float* b3    = (const float*)d_in[11];
  const float* W4    = (const float*)d_in[12];
  const float* b4    = (const float*)d_in[13];
  const float* W5    = (const float*)d_in[14];
  const float* b5    = (const float*)d_in[15];
  const float* W6    = (const float*)d_in[16];
  const float* b6    = (const float*)d_in[17];
  const float* Wp    = (const float*)d_in[18];
  const float* bp    = (const float*)d_in[19];

  // Workspace (96 MB peak), bf16 internals:
  //   W_hhb [0,24MB)   bf16 copy of W_hh (persistent)
  //   out1  [24,32MB)  4096x1024  — dead after layer2
  //   out2  [32,48MB)  4096x2048  — dead after xp GEMM
  //   xp    [48,96MB)  4096x6144  — live through GRU
  //   hs    [24,40MB)  (B,T,2048) — overlays out1+out2-head (dead)
  //   out_s [40,48MB)  4096x1024  — overlays out2 tail (dead)
  char* ws = (char*)d_ws;
  bf16_t* W_hhb = (bf16_t*)(ws);
  bf16_t* out1  = (bf16_t*)(ws + (24u << 20));
  bf16_t* out2  = (bf16_t*)(ws + (32u << 20));
  bf16_t* xp    = (bf16_t*)(ws + (48u << 20));
  bf16_t* hs    = (bf16_t*)(ws + (24u << 20));
  bf16_t* out_s = (bf16_t*)(ws + (40u << 20));
  float*  outp  = (float*)d_out;

  hipMemsetAsync(d_out, 0, (size_t)out_size * sizeof(float), stream);

  dim3 blk(256);
  // W_hh f32 -> bf16 (6144*2048 = 12,582,912 elems; /8 = 1,572,864)
  cvt_f32_bf16<<<dim3(6144), blk, 0, stream>>>(W_hh, W_hhb, 1572864);
  // layer1: (4096x32)*(1024x32)^T, relu
  gemm_bt<float, float><<<dim3(8, 32), blk, 0, stream>>>(x, W1, b1, out1, 4096, 1024, 32, 1);
  // layer2: (4096x1024)*(2048x1024)^T, relu
  gemm_bt<bf16_t, float><<<dim3(16, 32), blk, 0, stream>>>(out1, W2, b2, out2, 4096, 2048, 1024, 1);
  // xp: (4096x2048)*(6144x2048)^T + b_ih
  gemm_bt<bf16_t, float><<<dim3(48, 32), blk, 0, stream>>>(out2, W_ih, b_ih, xp, 4096, 6144, 2048, 0);
  // GRU scan; t=0 has h=0 (hprev==nullptr path)
  gru_step<<<dim3(256), blk, 0, stream>>>(W_hhb, b_hh, xp, hs, nullptr, 0);
  for (int t = 1; t < 128; ++t) {
    gru_step<<<dim3(256), blk, 0, stream>>>(W_hhb, b_hh, xp, hs,
                                            hs + (size_t)(t - 1) * 2048, t);
  }
  // layer3: (4096x2048)*(1024x2048)^T, relu
  gemm_bt<bf16_t, float><<<dim3(8, 32), blk, 0, stream>>>(hs, W3, b3, out_s, 4096, 1024, 2048, 1);
  // heads (f32 weights, f32 out)
  heads_kernel<<<dim3(4096), blk, 0, stream>>>(out_s, label, W4, b4, W5, b5, W6, b6, Wp, bp, outp);
}